// Round 5
// baseline (3570.827 us; speedup 1.0000x reference)
//
#include <hip/hip_runtime.h>
#include <math.h>

// Sparsemax along axis 0 of z = -exp(a)*x, x: (4096, 8192) f32 row-major.
// 8192 independent simplex projections over columns.
//
// R5: three streaming passes, replay-hardened.
//   R4 failed only under graph replay: its 9 MB ws footprint (never validated
//   against ws_size) + memset-initialized metadata made replays diverge.
//   R5 removes every init dependency: no atomics, no memset, no ws except a
//   32 KB tau array. All bulk scratch lives inside d_out (128 MiB) at a
//   64 MiB offset; each scratch word has exactly one writer and is written
//   before any reader runs (kernels are stream-ordered); the epilogue then
//   overwrites all of d_out with the real output.
//
//  1) scan:    thread owns (col, 256-row chunk): streaming prefix-filter
//              v > runmax-1 (superset of support: tau* >= colmax-1) into its
//              privately-owned CAP=32 slot array; writes chunk max + count.
//  2) solve:   1 thread/col: colmax = max of 16 chunk maxima; gather
//              candidates > colmax-1 (~6 survive); exact Michelot; tau -> ws.
//              Exact full-column fallback if any chunk count > CAP or K > 64.
//  3) epilogue: out = max(s*x - tau[col], 0), float4, fully coalesced;
//              overwrites every d_out element including the scratch region.
//
// tau is exact: support elements satisfy z > tau* >= colmax-1 >= chunkmax-1
// >= prefixmax-1, so they are always collected (or the chunk overflows and
// the column takes the exact fallback). Michelot on any support-superset
// converges to the exact tau.

constexpr int ROWS   = 4096;
constexpr int COLS   = 8192;
constexpr int CHUNK  = 256;              // rows per scan-chunk
constexpr int NCHUNK = ROWS / CHUNK;     // 16
constexpr int CAP    = 32;               // candidate slots per (col, chunk)

// scratch layout inside d_out, offsets in floats (d_out = 33,554,432 floats)
constexpr size_t OFF    = 16u * 1024 * 1024;          // 64 MiB in
constexpr size_t O_CMAX = OFF;                         // float[NCHUNK][COLS]
constexpr size_t O_CNT  = OFF + (size_t)NCHUNK * COLS; // int  [NCHUNK][COLS]
constexpr size_t O_CAND = OFF + 2u * NCHUNK * COLS;    // float[NCHUNK][COLS][CAP]
// ends at 16.75M + 4M floats = 21.2M floats < 33.5M  ✓

// ---- pass 1: streaming scan --------------------------------------------
// grid (COLS/64, NCHUNK/4), block 256. Wave w handles chunk blockIdx.y*4+w;
// lane l handles column blockIdx.x*64+l (64 consecutive cols = 256 B/instr,
// fully coalesced).
__global__ __launch_bounds__(256)
void scan_kernel(const float* __restrict__ x, const float* __restrict__ a,
                 float* __restrict__ outbuf)
{
    const int lane  = threadIdx.x & 63;
    const int wave  = threadIdx.x >> 6;
    const int col   = blockIdx.x * 64 + lane;
    const int chunk = blockIdx.y * 4 + wave;
    const float s   = -expf(a[0]);

    const float* p = x + (size_t)chunk * CHUNK * COLS + col;
    float* cmax = outbuf + O_CMAX;
    int*   cnt  = (int*)(outbuf + O_CNT);
    float* cb   = outbuf + O_CAND + ((size_t)chunk * COLS + col) * CAP;

    float runmax = -1e30f;
    int n = 0;
    #pragma unroll 8
    for (int i = 0; i < CHUNK; ++i) {
        const float v = s * p[(size_t)i * COLS];
        if (v > runmax - 1.0f) {          // prefix superset filter
            if (n < CAP) cb[n] = v;       // privately-owned slots, plain store
            ++n;
            runmax = fmaxf(runmax, v);
        }
    }
    cmax[chunk * COLS + col] = runmax;    // plain store, unique writer
    cnt [chunk * COLS + col] = n;         // n > CAP signals overflow to solve
}

// ---- pass 2: per-column exact solve ------------------------------------
__global__ __launch_bounds__(256)
void solve_kernel(const float* __restrict__ x, const float* __restrict__ a,
                  const float* __restrict__ outbuf, float* __restrict__ tau)
{
    const int col = blockIdx.x * 256 + threadIdx.x;
    const float* cmax = outbuf + O_CMAX;
    const int*   cnt  = (const int*)(outbuf + O_CNT);
    const float* cand = outbuf + O_CAND;

    float m = cmax[col];
    #pragma unroll
    for (int ch = 1; ch < NCHUNK; ++ch) m = fmaxf(m, cmax[ch * COLS + col]);
    const float thr = m - 1.0f;

    float buf[64];
    int K = 0;
    bool bad = false;
    for (int ch = 0; ch < NCHUNK; ++ch) {
        const int n = cnt[ch * COLS + col];
        if (n > CAP) { bad = true; break; }
        const float* cb = cand + ((size_t)ch * COLS + col) * CAP;
        for (int j = 0; j < n; ++j) {
            const float v = cb[j];
            if (v > thr) {
                if (K < 64) buf[K] = v;
                ++K;
            }
        }
    }
    if (K > 64) bad = true;

    float t = -1e30f, prev = -1.f;
    if (!bad) {
        // exact Michelot on candidate superset (K >= 1: colmax is in it)
        for (int it = 0; it < 70; ++it) {           // converges in <= K+1
            float ss = 0.f, sc = 0.f;
            for (int i = 0; i < K; ++i) {
                const float v = buf[i];
                if (v > t) { ss += v; sc += 1.f; }
            }
            t = (ss - 1.0f) / sc;
            if (sc == prev) break;
            prev = sc;
        }
    } else {
        // exact full-column Michelot straight from x (rare: P ~ 1e-3/col)
        const float s = -expf(a[0]);
        for (int it = 0; it < 4096; ++it) {         // support shrinks every iter
            float ss = 0.f, sc = 0.f;
            for (int r = 0; r < ROWS; ++r) {
                const float v = s * x[(size_t)r * COLS + col];
                if (v > t) { ss += v; sc += 1.f; }
            }
            t = (ss - 1.0f) / sc;
            if (sc == prev) break;
            prev = sc;
        }
    }
    tau[col] = t;
}

// ---- pass 3: elementwise epilogue --------------------------------------
__global__ __launch_bounds__(256)
void epilogue_kernel(const float* __restrict__ x, const float* __restrict__ a,
                     const float* __restrict__ tau, float* __restrict__ out)
{
    const size_t i4 = ((size_t)blockIdx.x * 256 + threadIdx.x) * 4;
    const float s = -expf(a[0]);
    const int col = (int)(i4 & (COLS - 1));          // multiple of 4
    const float4 v = *reinterpret_cast<const float4*>(x + i4);
    const float4 t = *reinterpret_cast<const float4*>(tau + col);
    float4 o;
    o.x = fmaxf(s * v.x - t.x, 0.f);
    o.y = fmaxf(s * v.y - t.y, 0.f);
    o.z = fmaxf(s * v.z - t.z, 0.f);
    o.w = fmaxf(s * v.w - t.w, 0.f);
    *reinterpret_cast<float4*>(out + i4) = o;
}

extern "C" void kernel_launch(void* const* d_in, const int* in_sizes, int n_in,
                              void* d_out, int out_size, void* d_ws, size_t ws_size,
                              hipStream_t stream) {
    const float* x = (const float*)d_in[0];
    const float* a = (const float*)d_in[1];
    float* out = (float*)d_out;
    float* tau = (float*)d_ws;               // 32 KB — only ws use

    hipLaunchKernelGGL(scan_kernel, dim3(COLS / 64, NCHUNK / 4), dim3(256), 0,
                       stream, x, a, out);
    hipLaunchKernelGGL(solve_kernel, dim3(COLS / 256), dim3(256), 0, stream,
                       x, a, out, tau);
    hipLaunchKernelGGL(epilogue_kernel, dim3((ROWS * COLS / 4) / 256), dim3(256),
                       0, stream, x, a, tau, out);
}

// Round 6
// 631.266 us; speedup vs baseline: 5.6566x; 5.6566x over previous
//
#include <hip/hip_runtime.h>
#include <math.h>

// Sparsemax along axis 0 of z = -exp(a)*x, x: (4096, 8192) f32 row-major.
// 8192 independent simplex projections over columns.
//
// R6: three streaming passes. R5's failure mode: prefix-filter survivor
// counts are positively correlated via the running max -> P(n > CAP) ~ 1e-3,
// and each overflow triggered a full-4096-row divergent fallback (ms-scale
// straggler waves -> solve took 3.26 ms). R6 makes overflow cheap:
//
//  1) scan:    thread owns (col, 256-row chunk): prefix-filter v > runmax-1
//              (superset of support: tau* >= colmax-1 >= prefix bounds) into
//              slot-major cand[ch][slot][col] (coalesced for solve); writes
//              chunk max + true count n (n > CAP flags partial storage).
//  2) solve:   1 thread/col, NO local buffer (R5's buf[64] spilled to
//              scratch). colmax = max of 16 chunk maxima; Michelot from
//              t0 = colmax-1 (valid lower bound, monotone convergence),
//              each iteration re-reads stored candidates (L2, coalesced);
//              overflowed chunks are re-streamed from x (256 rows only,
//              L3-resident) inside the same loop. Exact for any data.
//  3) epilogue: out = max(s*x - tau[col], 0), float4, fully coalesced;
//              overwrites all of d_out including the scratch region.
//
// Replay-safe by construction: no atomics, no memset, no ws except tau
// (32 KB); every scratch word read was written earlier in the same launch
// by its unique owner; bulk scratch lives inside d_out at a 64 MiB offset.

constexpr int ROWS   = 4096;
constexpr int COLS   = 8192;
constexpr int CHUNK  = 256;              // rows per scan-chunk
constexpr int NCHUNK = ROWS / CHUNK;     // 16
constexpr int CAP    = 48;               // candidate slots per (col, chunk)

// scratch layout inside d_out, offsets in floats (d_out = 33,554,432 floats)
constexpr size_t OFF    = 16u * 1024 * 1024;               // 64 MiB in
constexpr size_t O_CMAX = OFF;                             // float[NCHUNK][COLS]
constexpr size_t O_CNT  = O_CMAX + (size_t)NCHUNK * COLS;  // int  [NCHUNK][COLS]
constexpr size_t O_CAND = O_CNT  + (size_t)NCHUNK * COLS;  // float[NCHUNK][CAP][COLS]
// end = 16.78M + 0.26M + 6.29M = 23.3M floats < 33.5M  ✓

// ---- pass 1: streaming scan --------------------------------------------
// grid (COLS/64, NCHUNK/4), block 256. Wave w handles chunk blockIdx.y*4+w;
// lane l handles column blockIdx.x*64+l (64 consecutive cols = 256 B/instr).
__global__ __launch_bounds__(256)
void scan_kernel(const float* __restrict__ x, const float* __restrict__ a,
                 float* __restrict__ outbuf)
{
    const int lane  = threadIdx.x & 63;
    const int wave  = threadIdx.x >> 6;
    const int col   = blockIdx.x * 64 + lane;
    const int chunk = blockIdx.y * 4 + wave;
    const float s   = -expf(a[0]);

    const float* p = x + (size_t)chunk * CHUNK * COLS + col;
    float* cand = outbuf + O_CAND;

    float runmax = -1e30f;
    int n = 0;
    #pragma unroll 8
    for (int i = 0; i < CHUNK; ++i) {
        const float v = s * p[(size_t)i * COLS];
        if (v > runmax - 1.0f) {          // prefix superset filter
            if (n < CAP)                  // slot-major: coalesced for solve
                cand[((size_t)(chunk * CAP + n)) * COLS + col] = v;
            ++n;
            runmax = fmaxf(runmax, v);
        }
    }
    outbuf[O_CMAX + (size_t)chunk * COLS + col] = runmax;
    ((int*)(outbuf + O_CNT))[chunk * COLS + col] = n;   // n>CAP => partial
}

// ---- pass 2: per-column exact solve ------------------------------------
// grid (COLS/256), block 256. One thread per column, no local array.
__global__ __launch_bounds__(256)
void solve_kernel(const float* __restrict__ x, const float* __restrict__ a,
                  const float* __restrict__ outbuf, float* __restrict__ tau)
{
    const int col = blockIdx.x * 256 + threadIdx.x;
    const float* cmax = outbuf + O_CMAX;
    const int*   cnt  = (const int*)(outbuf + O_CNT);
    const float* cand = outbuf + O_CAND;
    const float  s    = -expf(a[0]);

    float m = cmax[col];
    int n[NCHUNK];
    n[0] = cnt[col];
    #pragma unroll
    for (int ch = 1; ch < NCHUNK; ++ch) {
        m = fmaxf(m, cmax[(size_t)ch * COLS + col]);
        n[ch] = cnt[ch * COLS + col];
    }

    // Michelot from t0 = colmax - 1 (<= tau*, so convergence is exact).
    // Support candidates: stored lists for good chunks, streamed 256-row
    // re-read of x for overflowed chunks (rare; L3-resident; cheap).
    float t = m - 1.0f, prev = -1.f;
    for (int it = 0; it < NCHUNK * CAP + CHUNK + 2; ++it) {
        float ss = 0.f, sc = 0.f;
        #pragma unroll
        for (int ch = 0; ch < NCHUNK; ++ch) {
            if (n[ch] <= CAP) {
                const float* cb = cand + (size_t)ch * CAP * COLS + col;
                for (int j = 0; j < n[ch]; ++j) {
                    const float v = cb[(size_t)j * COLS];
                    if (v > t) { ss += v; sc += 1.f; }
                }
            } else {
                const float* p = x + (size_t)ch * CHUNK * COLS + col;
                for (int r = 0; r < CHUNK; ++r) {
                    const float v = s * p[(size_t)r * COLS];
                    if (v > t) { ss += v; sc += 1.f; }
                }
            }
        }
        t = (ss - 1.0f) / sc;             // sc >= 1: colmax > colmax-1 = t0
        if (sc == prev) break;            // support fixed -> t == tau*
        prev = sc;
    }
    tau[col] = t;
}

// ---- pass 3: elementwise epilogue --------------------------------------
__global__ __launch_bounds__(256)
void epilogue_kernel(const float* __restrict__ x, const float* __restrict__ a,
                     const float* __restrict__ tau, float* __restrict__ out)
{
    const size_t i4 = ((size_t)blockIdx.x * 256 + threadIdx.x) * 4;
    const float s = -expf(a[0]);
    const int col = (int)(i4 & (COLS - 1));          // multiple of 4
    const float4 v = *reinterpret_cast<const float4*>(x + i4);
    const float4 t = *reinterpret_cast<const float4*>(tau + col);
    float4 o;
    o.x = fmaxf(s * v.x - t.x, 0.f);
    o.y = fmaxf(s * v.y - t.y, 0.f);
    o.z = fmaxf(s * v.z - t.z, 0.f);
    o.w = fmaxf(s * v.w - t.w, 0.f);
    *reinterpret_cast<float4*>(out + i4) = o;
}

extern "C" void kernel_launch(void* const* d_in, const int* in_sizes, int n_in,
                              void* d_out, int out_size, void* d_ws, size_t ws_size,
                              hipStream_t stream) {
    const float* x = (const float*)d_in[0];
    const float* a = (const float*)d_in[1];
    float* out = (float*)d_out;
    float* tau = (float*)d_ws;               // 32 KB — only ws use

    hipLaunchKernelGGL(scan_kernel, dim3(COLS / 64, NCHUNK / 4), dim3(256), 0,
                       stream, x, a, out);
    hipLaunchKernelGGL(solve_kernel, dim3(COLS / 256), dim3(256), 0, stream,
                       x, a, out, tau);
    hipLaunchKernelGGL(epilogue_kernel, dim3((ROWS * COLS / 4) / 256), dim3(256),
                       0, stream, x, a, tau, out);
}

// Round 7
// 325.555 us; speedup vs baseline: 10.9684x; 1.9390x over previous
//
#include <hip/hip_runtime.h>
#include <math.h>

// Sparsemax along axis 0 of z = -exp(a)*x, x: (4096, 8192) f32 row-major.
// 8192 independent simplex projections over columns.
//
// R7: three streaming passes.
//   R6 solve was latency-bound serial (1 thread/col, 1 load in flight,
//   32 blocks -> 0.1% VALUBusy, 292 us). R7 solve = one WAVE per column,
//   candidates gathered in 16 coalesced loads into registers, Michelot on
//   registers + shfl butterflies, full occupancy.
//
//  1) scan:    thread owns (4 cols, 64-row chunk): float4 loads (1KB/wave
//              instr); per-col prefix filter v > runmax-1 (superset of
//              support: tau* >= colmax-1 >= any prefix bound) into
//              per-column-contiguous cand[col][ch][slot]; writes chunk max
//              and true count n (n > CAP flags partial storage).
//  2) solve:   wave per column. Lane l holds slot l&15 of chunks 4k+(l>>4)
//              (16 coalesced 256B gathers). colmax via butterfly. Michelot
//              from t0 = colmax-1 (valid lower bound -> monotone, exact).
//              Overflowed chunks re-streamed from x (64 rows, 1 row/lane)
//              inside the loop via a ballot bitmask. Exact for any data.
//  3) epilogue: out = max(s*x - tau[col], 0), float4, fully coalesced;
//              overwrites all of d_out including the scratch region.
//
// Replay-safe: no atomics, no memset; ws holds only tau (32 KB); bulk
// scratch lives inside d_out at a 64 MiB offset, every word written by a
// unique owner before any reader runs; epilogue overwrites all of d_out.
// Poisoned (unwritten) cand slots are excluded by the slot<n masks.

constexpr int ROWS   = 4096;
constexpr int COLS   = 8192;
constexpr int CHUNK  = 64;               // rows per scan-chunk
constexpr int NCHUNK = ROWS / CHUNK;     // 64
constexpr int CAP    = 16;               // candidate slots per (col, chunk)
constexpr int CPC    = NCHUNK * CAP;     // 1024 floats of cand per column

// scratch layout inside d_out, offsets in floats (d_out = 33,554,432 floats)
constexpr size_t OFF    = 16u * 1024 * 1024;               // 64 MiB in
constexpr size_t O_CMAX = OFF;                             // float[COLS][NCHUNK]
constexpr size_t O_CNT  = O_CMAX + (size_t)COLS * NCHUNK;  // int  [COLS][NCHUNK]
constexpr size_t O_CAND = O_CNT  + (size_t)COLS * NCHUNK;  // float[COLS][NCHUNK][CAP]
// end = 16.78M + 0.52M + 0.52M + 8.39M = 26.2M floats < 33.5M  ✓

// ---- pass 1: streaming scan --------------------------------------------
// grid (2048/64=32, NCHUNK/4=16), block 256. Wave w handles chunk
// blockIdx.y*4+w; lane l handles column quad blockIdx.x*64+l (64 lanes x
// 16B = 1KB contiguous per load instruction).
__global__ __launch_bounds__(256)
void scan_kernel(const float* __restrict__ x, const float* __restrict__ a,
                 float* __restrict__ outbuf)
{
    const int lane  = threadIdx.x & 63;
    const int wave  = threadIdx.x >> 6;
    const int col0  = (blockIdx.x * 64 + lane) * 4;
    const int chunk = blockIdx.y * 4 + wave;
    const float s   = -expf(a[0]);

    const float* p = x + (size_t)chunk * CHUNK * COLS + col0;
    float* cb0 = outbuf + O_CAND + (size_t)col0 * CPC + chunk * CAP;

    float rm[4] = {-1e30f, -1e30f, -1e30f, -1e30f};
    int   n[4]  = {0, 0, 0, 0};
    #pragma unroll 8
    for (int i = 0; i < CHUNK; ++i) {
        const float4 v4 = *reinterpret_cast<const float4*>(p + (size_t)i * COLS);
        const float v[4] = {s * v4.x, s * v4.y, s * v4.z, s * v4.w};
        #pragma unroll
        for (int c = 0; c < 4; ++c) {
            if (v[c] > rm[c] - 1.0f) {        // prefix superset filter
                if (n[c] < CAP) cb0[(size_t)c * CPC + n[c]] = v[c];
                ++n[c];
                rm[c] = fmaxf(rm[c], v[c]);
            }
        }
    }
    #pragma unroll
    for (int c = 0; c < 4; ++c) {
        outbuf[O_CMAX + (size_t)(col0 + c) * NCHUNK + chunk] = rm[c];
        ((int*)(outbuf + O_CNT))[(size_t)(col0 + c) * NCHUNK + chunk] = n[c];
    }
}

// ---- pass 2: wave-per-column exact solve -------------------------------
// grid (COLS/4 = 2048), block 256 (4 waves = 4 columns).
__global__ __launch_bounds__(256)
void solve_kernel(const float* __restrict__ x, const float* __restrict__ a,
                  const float* __restrict__ outbuf, float* __restrict__ tau)
{
    const int lane = threadIdx.x & 63;
    const int wave = threadIdx.x >> 6;
    const int col  = blockIdx.x * 4 + wave;
    const float s  = -expf(a[0]);

    const float* cmax_c = outbuf + O_CMAX + (size_t)col * NCHUNK;
    const int*   cnt_c  = (const int*)(outbuf + O_CNT) + (size_t)col * NCHUNK;
    const float* cand_c = outbuf + O_CAND + (size_t)col * CPC;

    // gather candidates: lane l holds position l+64k = (ch=4k+(l>>4), slot=l&15)
    float v[16];
    #pragma unroll
    for (int k = 0; k < 16; ++k) v[k] = cand_c[lane + 64 * k];

    const float mxl = cmax_c[lane];           // chunk-lane maxima (64 chunks)
    const int   nv  = cnt_c[lane];            // chunk-lane counts
    float mx = mxl;
    #pragma unroll
    for (int m = 1; m < 64; m <<= 1) mx = fmaxf(mx, __shfl_xor(mx, m, 64));

    bool valid[16];
    #pragma unroll
    for (int k = 0; k < 16; ++k) {
        const int ch = 4 * k + (lane >> 4);
        const int nk = __shfl(nv, ch, 64);    // count of chunk ch
        valid[k] = (nk <= CAP) && ((lane & 15) < nk);
    }
    const unsigned long long ovf = __ballot(nv > CAP);  // bit ch = overflow

    // Michelot from t0 = colmax-1 (<= tau*): monotone, exact convergence.
    float t = mx - 1.0f, prev = -1.0f;
    for (int it = 0; it < ROWS + 4; ++it) {   // support shrinks every iter
        float ss = 0.f, sc = 0.f;
        #pragma unroll
        for (int k = 0; k < 16; ++k) {
            if (valid[k] && v[k] > t) { ss += v[k]; sc += 1.f; }
        }
        unsigned long long m = ovf;           // rare: re-stream 64-row chunks
        while (m) {
            const int ch = __builtin_ctzll(m);
            m &= m - 1;
            const float w = s * x[((size_t)ch * CHUNK + lane) * COLS + col];
            if (w > t) { ss += w; sc += 1.f; }
        }
        #pragma unroll
        for (int b = 1; b < 64; b <<= 1) {
            ss += __shfl_xor(ss, b, 64);
            sc += __shfl_xor(sc, b, 64);
        }
        t = (ss - 1.0f) / sc;                 // sc >= 1: colmax > t always
        if (sc == prev) break;
        prev = sc;
    }
    if (lane == 0) tau[col] = t;
}

// ---- pass 3: elementwise epilogue --------------------------------------
__global__ __launch_bounds__(256)
void epilogue_kernel(const float* __restrict__ x, const float* __restrict__ a,
                     const float* __restrict__ tau, float* __restrict__ out)
{
    const size_t i4 = ((size_t)blockIdx.x * 256 + threadIdx.x) * 4;
    const float s = -expf(a[0]);
    const int col = (int)(i4 & (COLS - 1));          // multiple of 4
    const float4 v = *reinterpret_cast<const float4*>(x + i4);
    const float4 t = *reinterpret_cast<const float4*>(tau + col);
    float4 o;
    o.x = fmaxf(s * v.x - t.x, 0.f);
    o.y = fmaxf(s * v.y - t.y, 0.f);
    o.z = fmaxf(s * v.z - t.z, 0.f);
    o.w = fmaxf(s * v.w - t.w, 0.f);
    *reinterpret_cast<float4*>(out + i4) = o;
}

extern "C" void kernel_launch(void* const* d_in, const int* in_sizes, int n_in,
                              void* d_out, int out_size, void* d_ws, size_t ws_size,
                              hipStream_t stream) {
    const float* x = (const float*)d_in[0];
    const float* a = (const float*)d_in[1];
    float* out = (float*)d_out;
    float* tau = (float*)d_ws;               // 32 KB — only ws use

    hipLaunchKernelGGL(scan_kernel, dim3((COLS / 4) / 64, NCHUNK / 4), dim3(256),
                       0, stream, x, a, out);
    hipLaunchKernelGGL(solve_kernel, dim3(COLS / 4), dim3(256), 0, stream,
                       x, a, out, tau);
    hipLaunchKernelGGL(epilogue_kernel, dim3((ROWS * COLS / 4) / 256), dim3(256),
                       0, stream, x, a, tau, out);
}